// Round 7
// baseline (98.040 us; speedup 1.0000x reference)
//
#include <hip/hip_runtime.h>
#include <math.h>

#define BB 2
#define NN 4096
#define CC 33
#define RP 40                         // bf16 row pitch in ushorts (80 B, 16B-aligned)
#define TILE 64
#define NTILES (NN / TILE)            // 64
#define NTRI ((NTILES * (NTILES + 1)) / 2)  // 2080 upper-triangle tiles per batch
#define ROWBLK ((BB * NN) / 4)        // 2048 row-kernel blocks (4 waves = 4 rows each)
#define PAIRBLK (BB * NTRI)           // 4160 pair-kernel blocks (16.25/CU -> latency hidden)

typedef __attribute__((ext_vector_type(8))) short frag_ab;   // 8 bf16 (4 VGPRs)
typedef __attribute__((ext_vector_type(4))) float f32x4;     // 4 fp32 accum

__device__ __forceinline__ float fast_sqrt(float x) {
    return __builtin_amdgcn_sqrtf(x);                        // v_sqrt_f32, ~2 ULP
}
__device__ __forceinline__ unsigned short f2bf(float x) {
    unsigned u = __float_as_uint(x);
    return (unsigned short)((u + 0x7FFFu + ((u >> 16) & 1u)) >> 16);  // RNE, x>=0 finite
}
__device__ __forceinline__ float bf2f(unsigned short b) {
    return __uint_as_float(((unsigned)b) << 16);
}

// ---------------- kernel 1: per-row softmax -> bf16 probs + partials --------
__global__ __launch_bounds__(256) void row_kernel(
    const float* __restrict__ pred, const int* __restrict__ targets,
    const int* __restrict__ pred_choice, unsigned short* __restrict__ p16,
    float* __restrict__ sqn, float2* __restrict__ part_row,
    int* __restrict__ part_match, unsigned* __restrict__ done)
{
    __shared__ float2 lds_cf[4];
    __shared__ int lds_mt[4];

    if (blockIdx.x == 0 && threadIdx.x == 0) *done = 0u;   // reset winner counter
                                                           // (stream-ordered before pair_kernel)
    int lane = threadIdx.x & 63;
    int wave = threadIdx.x >> 6;
    int row = blockIdx.x * 4 + wave;

    float v = (lane < CC) ? pred[(size_t)row * CC + lane] : -INFINITY;

    float m = v;
    #pragma unroll
    for (int off = 32; off; off >>= 1) m = fmaxf(m, __shfl_xor(m, off));

    float e = (lane < CC) ? __expf(v - m) : 0.0f;
    float s = e;
    #pragma unroll
    for (int off = 32; off; off >>= 1) s += __shfl_xor(s, off);

    float pv = e / s;                        // 0 for lanes >= 33

    unsigned short pb = f2bf(pv);            // bf16-rounded prob (0 stays 0)
    if (lane < RP) p16[(size_t)row * RP + lane] = pb;

    float pf = bf2f(pb);                     // sqn in ROUNDED space (matches MFMA dots)
    float sq = pf * pf;
    #pragma unroll
    for (int off = 32; off; off >>= 1) sq += __shfl_xor(sq, off);

    int t = targets[row];
    float vt = __shfl(v, t);
    float pt = __shfl(pv, t);
    float logpt = (vt - m) - __logf(s);

    if (lane == 0) {
        sqn[row] = sq;
        float om = 1.0f - pt;
        lds_cf[wave] = make_float2(-logpt, om * om);
        lds_mt[wave] = (t == pred_choice[row]) ? 1 : 0;
    }
    __syncthreads();
    if (threadIdx.x == 0) {
        float2 a = lds_cf[0], b = lds_cf[1], c = lds_cf[2], d = lds_cf[3];
        part_row[blockIdx.x] = make_float2(a.x + b.x + c.x + d.x,
                                           a.y + b.y + c.y + d.y);
        part_match[blockIdx.x] = lds_mt[0] + lds_mt[1] + lds_mt[2] + lds_mt[3];
    }
}

// ---------------- kernel 2: 64x64 Gram tile via bf16 MFMA + fused finalize --
// LDS: [64 rows][40 ushorts] linear (80B pitch rotates b128 reads across all
// 8 bank groups -> <=2-way, free; staging is a linear 16B/lane memcpy).
// Classes 0..31: one mfma_f32_16x16x32_bf16 per 16x16 subtile; class 32: fp32
// rank-1 update. Last finished block reduces all partials and writes d_out.
__global__ __launch_bounds__(256) void pair_kernel(
    const unsigned short* __restrict__ p16, const float* __restrict__ sqn,
    float* __restrict__ part_pair, const float2* __restrict__ part_row,
    const int* __restrict__ part_match, unsigned* __restrict__ done,
    float* __restrict__ out)
{
    __shared__ __align__(16) unsigned short spi[TILE * RP];
    __shared__ __align__(16) unsigned short spj[TILE * RP];
    __shared__ float ssqi[TILE], ssqj[TILE];
    __shared__ float red[4];
    __shared__ int lastFlag;
    __shared__ double lds_ce[4], lds_fo[4], lds_pr[4];
    __shared__ int lds_mt[4];

    int bid = blockIdx.x;
    int b = bid / NTRI;
    int t = bid % NTRI;

    // decode (ti, tj), ti <= tj, row-major upper triangle
    float disc = (NTILES + 0.5f) * (NTILES + 0.5f) - 2.0f * (float)t;
    int ti = (int)(NTILES + 0.5f - fast_sqrt(disc));
    if (ti < 0) ti = 0;
    if (ti > NTILES - 1) ti = NTILES - 1;
    while (ti > 0 && (ti * NTILES - ti * (ti - 1) / 2) > t) --ti;
    while (((ti + 1) * NTILES - (ti + 1) * ti / 2) <= t) ++ti;
    int tj = ti + (t - (ti * NTILES - ti * (ti - 1) / 2));

    int i0 = ti * TILE, j0 = tj * TILE;

    // linear staging: each tile is a contiguous 5120B block of p16
    const float4* srci = (const float4*)(p16 + ((size_t)b * NN + i0) * RP);
    const float4* srcj = (const float4*)(p16 + ((size_t)b * NN + j0) * RP);
    float4* di = (float4*)spi;
    float4* dj = (float4*)spj;
    for (int k = threadIdx.x; k < TILE * (RP / 8); k += 256) {  // 320 float4 each
        di[k] = srci[k];
        dj[k] = srcj[k];
    }
    if (threadIdx.x < TILE)
        ssqi[threadIdx.x] = sqn[b * NN + i0 + threadIdx.x];
    else if (threadIdx.x < 2 * TILE)
        ssqj[threadIdx.x - TILE] = sqn[b * NN + j0 + (threadIdx.x - TILE)];
    __syncthreads();

    int l = threadIdx.x & 63;
    int w = threadIdx.x >> 6;          // wave = 16-row strip of the i-tile
    int col = l & 15;
    int kc = l >> 4;                   // k-chunk 0..3 (8 bf16 each)

    // A fragment: rows 16w..16w+15 of i-tile, k = kc*8..kc*8+7
    frag_ab afr = *(const frag_ab*)&spi[(16 * w + col) * RP + kc * 8];

    // per-lane row metadata (C layout: col=lane&15, row=(lane>>4)*4+r)
    float qi[4], c32a[4];
    int gi[4];
    #pragma unroll
    for (int r = 0; r < 4; r++) {
        int ir = 16 * w + kc * 4 + r;
        qi[r]   = ssqi[ir];
        c32a[r] = bf2f(spi[ir * RP + 32]);
        gi[r]   = i0 + ir;
    }

    float ssum = 0.0f;
    bool diag = (ti == tj);

    #pragma unroll
    for (int n = 0; n < 4; n++) {      // 16-col subtiles of the j-tile
        frag_ab bfr = *(const frag_ab*)&spj[(16 * n + col) * RP + kc * 8];
        f32x4 acc = {0.0f, 0.0f, 0.0f, 0.0f};
        acc = __builtin_amdgcn_mfma_f32_16x16x32_bf16(afr, bfr, acc, 0, 0, 0);

        float c32b = bf2f(spj[(16 * n + col) * RP + 32]);
        float qj   = ssqj[16 * n + col];
        int   gj   = j0 + 16 * n + col;

        #pragma unroll
        for (int r = 0; r < 4; r++) {
            float g  = fmaf(c32a[r], c32b, acc[r]);      // + class-32 term
            float d2 = fmaf(-2.0f, g, qi[r] + qj);
            float d  = (d2 > 0.0f) ? fast_sqrt(d2) : 0.0f;
            ssum += (!diag || gj > gi[r]) ? d : 0.0f;    // strict upper on diag tiles
        }
    }

    #pragma unroll
    for (int off = 32; off; off >>= 1) ssum += __shfl_xor(ssum, off);
    if (l == 0) red[w] = ssum;
    __syncthreads();

    if (threadIdx.x == 0) {
        part_pair[bid] = red[0] + red[1] + red[2] + red[3];
        __threadfence();                               // release partial
        unsigned old = atomicAdd(done, 1u);
        lastFlag = (old == (unsigned)(PAIRBLK - 1)) ? 1 : 0;
    }
    __syncthreads();
    if (!lastFlag) return;
    __threadfence();                                   // acquire all partials

    // ---- fused finalize (winner block only) ----
    double ce = 0.0, fo = 0.0, pr = 0.0;
    int mt = 0;
    for (int i = threadIdx.x; i < ROWBLK; i += 256) {
        float2 v = part_row[i];
        ce += (double)v.x;
        fo += (double)v.y;
        mt += part_match[i];
    }
    for (int i = threadIdx.x; i < PAIRBLK; i += 256)
        pr += (double)part_pair[i];

    #pragma unroll
    for (int off = 32; off; off >>= 1) {
        ce += __shfl_xor(ce, off);
        fo += __shfl_xor(fo, off);
        pr += __shfl_xor(pr, off);
        mt += __shfl_xor(mt, off);
    }
    if (l == 0) { lds_ce[w] = ce; lds_fo[w] = fo; lds_pr[w] = pr; lds_mt[w] = mt; }
    __syncthreads();
    if (threadIdx.x == 0) {
        double tce = lds_ce[0] + lds_ce[1] + lds_ce[2] + lds_ce[3];
        double tfo = lds_fo[0] + lds_fo[1] + lds_fo[2] + lds_fo[3];
        double tpr = lds_pr[0] + lds_pr[1] + lds_pr[2] + lds_pr[3];
        int    tmt = lds_mt[0] + lds_mt[1] + lds_mt[2] + lds_mt[3];

        double BN = (double)(BB * NN);
        double loss = (tce / BN) * (tfo / BN);
        double dice = 1.0 - 2.0 * ((double)tmt + 1.0) / (2.0 * BN + 1.0);
        double S = 2.0 * tpr;                    // full matrix sum (diag = 0)
        double mean_pred = S / (BN * (double)NN);
        double dml = 0.05 * log(0.05) - 0.05 * mean_pred;
        out[0] = (float)(loss + dice + dml);
    }
}

extern "C" void kernel_launch(void* const* d_in, const int* in_sizes, int n_in,
                              void* d_out, int out_size, void* d_ws, size_t ws_size,
                              hipStream_t stream)
{
    const float* pred        = (const float*)d_in[0];
    // d_in[1] = y_ohe: unused — the double-where provably collapses dis_map to 0.05
    const int*   targets     = (const int*)d_in[2];
    const int*   pred_choice = (const int*)d_in[3];

    char* ws = (char*)d_ws;
    size_t off = 0;
    unsigned short* p16 = (unsigned short*)ws;               // BB*NN*RP ushorts
    off += (size_t)BB * NN * RP * sizeof(unsigned short);
    float* sqn = (float*)(ws + off);
    off += (size_t)BB * NN * sizeof(float);
    off = (off + 15) & ~(size_t)15;
    float2* part_row = (float2*)(ws + off);                  // ROWBLK float2
    off += (size_t)ROWBLK * sizeof(float2);
    int* part_match = (int*)(ws + off);                      // ROWBLK int
    off += (size_t)ROWBLK * sizeof(int);
    float* part_pair = (float*)(ws + off);                   // PAIRBLK float
    off += (size_t)PAIRBLK * sizeof(float);
    unsigned* done = (unsigned*)(ws + off);                  // winner counter
    off += sizeof(unsigned);

    row_kernel<<<ROWBLK, 256, 0, stream>>>(pred, targets, pred_choice,
                                           p16, sqn, part_row, part_match, done);
    pair_kernel<<<PAIRBLK, 256, 0, stream>>>(p16, sqn, part_pair, part_row,
                                             part_match, done, (float*)d_out);
}

// Round 8
// 23.455 us; speedup vs baseline: 4.1800x; 4.1800x over previous
//
#include <hip/hip_runtime.h>
#include <math.h>

#define BB 2
#define NN 4096
#define CC 33
#define RP 40                         // bf16 row pitch in ushorts (80 B, 16B-aligned)
#define TILE 64
#define NTILES (NN / TILE)            // 64
#define NTRI ((NTILES * (NTILES + 1)) / 2)  // 2080 upper-triangle tiles per batch
#define ROWBLK ((BB * NN) / 4)        // 2048 row-kernel blocks (4 waves = 4 rows each)
#define PAIRBLK (BB * NTRI)           // 4160 pair-kernel blocks = 65 per slot x 64 slots
#define NSLOT 64
#define SLOTSTR 32                    // 32 words = 128 B between slots (distinct L2 lines)

typedef __attribute__((ext_vector_type(8))) short frag_ab;   // 8 bf16 (4 VGPRs)
typedef __attribute__((ext_vector_type(4))) float f32x4;     // 4 fp32 accum

__device__ __forceinline__ float fast_sqrt(float x) {
    return __builtin_amdgcn_sqrtf(x);                        // v_sqrt_f32, ~2 ULP
}
__device__ __forceinline__ unsigned short f2bf(float x) {
    unsigned u = __float_as_uint(x);
    return (unsigned short)((u + 0x7FFFu + ((u >> 16) & 1u)) >> 16);  // RNE, x>=0 finite
}
__device__ __forceinline__ float bf2f(unsigned short b) {
    return __uint_as_float(((unsigned)b) << 16);
}

// ---------------- kernel 1: per-row softmax -> bf16 probs + partials --------
// Block 0 additionally zeroes the atomic slot region (stream-ordered before
// pair_kernel, re-done every call -> graph-replay safe).
__global__ __launch_bounds__(256) void row_kernel(
    const float* __restrict__ pred, const int* __restrict__ targets,
    const int* __restrict__ pred_choice, unsigned short* __restrict__ p16,
    float* __restrict__ sqn, float2* __restrict__ part_row,
    int* __restrict__ part_match, float* __restrict__ slotf,
    unsigned* __restrict__ subcnt, unsigned* __restrict__ master)
{
    __shared__ float2 lds_cf[4];
    __shared__ int lds_mt[4];

    if (blockIdx.x == 0) {
        for (int i = threadIdx.x; i < NSLOT * SLOTSTR; i += 256) {
            slotf[i] = 0.0f;
            subcnt[i] = 0u;
        }
        if (threadIdx.x == 0) *master = 0u;
    }

    int lane = threadIdx.x & 63;
    int wave = threadIdx.x >> 6;
    int row = blockIdx.x * 4 + wave;

    float v = (lane < CC) ? pred[(size_t)row * CC + lane] : -INFINITY;

    float m = v;
    #pragma unroll
    for (int off = 32; off; off >>= 1) m = fmaxf(m, __shfl_xor(m, off));

    float e = (lane < CC) ? __expf(v - m) : 0.0f;
    float s = e;
    #pragma unroll
    for (int off = 32; off; off >>= 1) s += __shfl_xor(s, off);

    float pv = e / s;                        // 0 for lanes >= 33

    unsigned short pb = f2bf(pv);            // bf16-rounded prob (0 stays 0)
    if (lane < RP) p16[(size_t)row * RP + lane] = pb;

    float pf = bf2f(pb);                     // sqn in ROUNDED space (matches MFMA dots)
    float sq = pf * pf;
    #pragma unroll
    for (int off = 32; off; off >>= 1) sq += __shfl_xor(sq, off);

    int t = targets[row];
    float vt = __shfl(v, t);
    float pt = __shfl(pv, t);
    float logpt = (vt - m) - __logf(s);

    if (lane == 0) {
        sqn[row] = sq;
        float om = 1.0f - pt;
        lds_cf[wave] = make_float2(-logpt, om * om);
        lds_mt[wave] = (t == pred_choice[row]) ? 1 : 0;
    }
    __syncthreads();
    if (threadIdx.x == 0) {
        float2 a = lds_cf[0], b = lds_cf[1], c = lds_cf[2], d = lds_cf[3];
        part_row[blockIdx.x] = make_float2(a.x + b.x + c.x + d.x,
                                           a.y + b.y + c.y + d.y);
        part_match[blockIdx.x] = lds_mt[0] + lds_mt[1] + lds_mt[2] + lds_mt[3];
    }
}

// ---------------- kernel 2: 64x64 Gram tile via bf16 MFMA + fence-free fused
// finalize. Partial sums go through coherence-point atomics (sc1, L2-bypass):
// no __threadfence / buffer_wbl2 anywhere. 2-level completion counting:
// 65 blocks per slot -> slot winner increments master -> 64th = finalizer.
__global__ __launch_bounds__(256) void pair_kernel(
    const unsigned short* __restrict__ p16, const float* __restrict__ sqn,
    const float2* __restrict__ part_row, const int* __restrict__ part_match,
    float* __restrict__ slotf, unsigned* __restrict__ subcnt,
    unsigned* __restrict__ master, float* __restrict__ out)
{
    __shared__ __align__(16) unsigned short spi[TILE * RP];
    __shared__ __align__(16) unsigned short spj[TILE * RP];
    __shared__ float ssqi[TILE], ssqj[TILE];
    __shared__ float red[4];
    __shared__ int lastFlag;
    __shared__ double lds_ce[4], lds_fo[4], lds_pr[4];
    __shared__ int lds_mt[4];

    int bid = blockIdx.x;
    int b = bid / NTRI;
    int t = bid % NTRI;

    // decode (ti, tj), ti <= tj, row-major upper triangle
    float disc = (NTILES + 0.5f) * (NTILES + 0.5f) - 2.0f * (float)t;
    int ti = (int)(NTILES + 0.5f - fast_sqrt(disc));
    if (ti < 0) ti = 0;
    if (ti > NTILES - 1) ti = NTILES - 1;
    while (ti > 0 && (ti * NTILES - ti * (ti - 1) / 2) > t) --ti;
    while (((ti + 1) * NTILES - (ti + 1) * ti / 2) <= t) ++ti;
    int tj = ti + (t - (ti * NTILES - ti * (ti - 1) / 2));

    int i0 = ti * TILE, j0 = tj * TILE;

    // linear staging: each tile is a contiguous 5120B block of p16
    const float4* srci = (const float4*)(p16 + ((size_t)b * NN + i0) * RP);
    const float4* srcj = (const float4*)(p16 + ((size_t)b * NN + j0) * RP);
    float4* di = (float4*)spi;
    float4* dj = (float4*)spj;
    for (int k = threadIdx.x; k < TILE * (RP / 8); k += 256) {  // 320 float4 each
        di[k] = srci[k];
        dj[k] = srcj[k];
    }
    if (threadIdx.x < TILE)
        ssqi[threadIdx.x] = sqn[b * NN + i0 + threadIdx.x];
    else if (threadIdx.x < 2 * TILE)
        ssqj[threadIdx.x - TILE] = sqn[b * NN + j0 + (threadIdx.x - TILE)];
    __syncthreads();

    int l = threadIdx.x & 63;
    int w = threadIdx.x >> 6;          // wave = 16-row strip of the i-tile
    int col = l & 15;
    int kc = l >> 4;                   // k-chunk 0..3 (8 bf16 each)

    // A fragment: rows 16w..16w+15 of i-tile, k = kc*8..kc*8+7
    frag_ab afr = *(const frag_ab*)&spi[(16 * w + col) * RP + kc * 8];

    // per-lane row metadata (C layout: col=lane&15, row=(lane>>4)*4+r)
    float qi[4], c32a[4];
    int gi[4];
    #pragma unroll
    for (int r = 0; r < 4; r++) {
        int ir = 16 * w + kc * 4 + r;
        qi[r]   = ssqi[ir];
        c32a[r] = bf2f(spi[ir * RP + 32]);
        gi[r]   = i0 + ir;
    }

    float ssum = 0.0f;
    bool diag = (ti == tj);

    #pragma unroll
    for (int n = 0; n < 4; n++) {      // 16-col subtiles of the j-tile
        frag_ab bfr = *(const frag_ab*)&spj[(16 * n + col) * RP + kc * 8];
        f32x4 acc = {0.0f, 0.0f, 0.0f, 0.0f};
        acc = __builtin_amdgcn_mfma_f32_16x16x32_bf16(afr, bfr, acc, 0, 0, 0);

        float c32b = bf2f(spj[(16 * n + col) * RP + 32]);
        float qj   = ssqj[16 * n + col];
        int   gj   = j0 + 16 * n + col;

        #pragma unroll
        for (int r = 0; r < 4; r++) {
            float g  = fmaf(c32a[r], c32b, acc[r]);      // + class-32 term
            float d2 = fmaf(-2.0f, g, qi[r] + qj);
            float d  = (d2 > 0.0f) ? fast_sqrt(d2) : 0.0f;
            ssum += (!diag || gj > gi[r]) ? d : 0.0f;    // strict upper on diag tiles
        }
    }

    #pragma unroll
    for (int off = 32; off; off >>= 1) ssum += __shfl_xor(ssum, off);
    if (l == 0) red[w] = ssum;
    __syncthreads();

    if (threadIdx.x == 0) {
        float blockSum = red[0] + red[1] + red[2] + red[3];
        int slot = (bid & (NSLOT - 1)) * SLOTSTR;
        __hip_atomic_fetch_add(&slotf[slot], blockSum,
                               __ATOMIC_RELAXED, __HIP_MEMORY_SCOPE_AGENT);
        asm volatile("s_waitcnt vmcnt(0)" ::: "memory");   // order fadd before count
        unsigned o = __hip_atomic_fetch_add(&subcnt[slot], 1u,
                                            __ATOMIC_RELAXED, __HIP_MEMORY_SCOPE_AGENT);
        int last = 0;
        if (o == (PAIRBLK / NSLOT) - 1) {                  // 65th block of this slot
            unsigned o2 = __hip_atomic_fetch_add(master, 1u,
                                                 __ATOMIC_RELAXED, __HIP_MEMORY_SCOPE_AGENT);
            last = (o2 == NSLOT - 1);
        }
        lastFlag = last;
    }
    __syncthreads();
    if (!lastFlag) return;

    // ---- fused finalize (winner block only; all inputs coherent:
    //      slots via agent atomics, part_* via kernel-boundary) ----
    double ce = 0.0, fo = 0.0, pr = 0.0;
    int mt = 0;
    for (int i = threadIdx.x; i < ROWBLK; i += 256) {
        float2 v = part_row[i];
        ce += (double)v.x;
        fo += (double)v.y;
        mt += part_match[i];
    }
    for (int i = threadIdx.x; i < NSLOT; i += 256)
        pr += (double)__hip_atomic_load(&slotf[i * SLOTSTR],
                                        __ATOMIC_RELAXED, __HIP_MEMORY_SCOPE_AGENT);

    #pragma unroll
    for (int off = 32; off; off >>= 1) {
        ce += __shfl_xor(ce, off);
        fo += __shfl_xor(fo, off);
        pr += __shfl_xor(pr, off);
        mt += __shfl_xor(mt, off);
    }
    if (l == 0) { lds_ce[w] = ce; lds_fo[w] = fo; lds_pr[w] = pr; lds_mt[w] = mt; }
    __syncthreads();
    if (threadIdx.x == 0) {
        double tce = lds_ce[0] + lds_ce[1] + lds_ce[2] + lds_ce[3];
        double tfo = lds_fo[0] + lds_fo[1] + lds_fo[2] + lds_fo[3];
        double tpr = lds_pr[0] + lds_pr[1] + lds_pr[2] + lds_pr[3];
        int    tmt = lds_mt[0] + lds_mt[1] + lds_mt[2] + lds_mt[3];

        double BN = (double)(BB * NN);
        double loss = (tce / BN) * (tfo / BN);
        double dice = 1.0 - 2.0 * ((double)tmt + 1.0) / (2.0 * BN + 1.0);
        double S = 2.0 * tpr;                    // full matrix sum (diag = 0)
        double mean_pred = S / (BN * (double)NN);
        double dml = 0.05 * log(0.05) - 0.05 * mean_pred;
        out[0] = (float)(loss + dice + dml);
    }
}

extern "C" void kernel_launch(void* const* d_in, const int* in_sizes, int n_in,
                              void* d_out, int out_size, void* d_ws, size_t ws_size,
                              hipStream_t stream)
{
    const float* pred        = (const float*)d_in[0];
    // d_in[1] = y_ohe: unused — the double-where provably collapses dis_map to 0.05
    const int*   targets     = (const int*)d_in[2];
    const int*   pred_choice = (const int*)d_in[3];

    char* ws = (char*)d_ws;
    size_t off = 0;
    unsigned short* p16 = (unsigned short*)ws;               // BB*NN*RP ushorts
    off += (size_t)BB * NN * RP * sizeof(unsigned short);
    float* sqn = (float*)(ws + off);
    off += (size_t)BB * NN * sizeof(float);
    off = (off + 127) & ~(size_t)127;
    float2* part_row = (float2*)(ws + off);                  // ROWBLK float2
    off += (size_t)ROWBLK * sizeof(float2);
    int* part_match = (int*)(ws + off);                      // ROWBLK int
    off += (size_t)ROWBLK * sizeof(int);
    off = (off + 127) & ~(size_t)127;
    float* slotf = (float*)(ws + off);                       // 64 slots x 128 B
    off += (size_t)NSLOT * SLOTSTR * sizeof(float);
    unsigned* subcnt = (unsigned*)(ws + off);                // 64 counters x 128 B
    off += (size_t)NSLOT * SLOTSTR * sizeof(unsigned);
    unsigned* master = (unsigned*)(ws + off);
    off += sizeof(unsigned);

    row_kernel<<<ROWBLK, 256, 0, stream>>>(pred, targets, pred_choice,
                                           p16, sqn, part_row, part_match,
                                           slotf, subcnt, master);
    pair_kernel<<<PAIRBLK, 256, 0, stream>>>(p16, sqn, part_row, part_match,
                                             slotf, subcnt, master, (float*)d_out);
}

// Round 9
// 21.887 us; speedup vs baseline: 4.4794x; 1.0716x over previous
//
#include <hip/hip_runtime.h>
#include <math.h>

#define BB 2
#define NN 4096
#define CC 33
#define RP 40                         // bf16 row pitch in ushorts (80 B, 16B-aligned)
#define TILE 64
#define NTILES (NN / TILE)            // 64
#define NPB 1056                      // 64x128 blocks per batch: sum ceil((64-ti)/2)
#define ROWBLK ((BB * NN) / 8)        // 1024 row-kernel blocks (8 waves = 8 rows each)
#define PAIRBLK (BB * NPB)            // 2112 pair blocks = 33 per slot x 64 slots
#define NSLOT 64
#define SLOTSTR 32                    // 32 words = 128 B between slots (distinct L2 lines)

typedef __attribute__((ext_vector_type(8))) short frag_ab;   // 8 bf16 (4 VGPRs)
typedef __attribute__((ext_vector_type(4))) float f32x4;     // 4 fp32 accum

__device__ __forceinline__ float fast_sqrt(float x) {
    return __builtin_amdgcn_sqrtf(x);                        // v_sqrt_f32, ~2 ULP
}
__device__ __forceinline__ unsigned short f2bf(float x) {
    unsigned u = __float_as_uint(x);
    return (unsigned short)((u + 0x7FFFu + ((u >> 16) & 1u)) >> 16);  // RNE, x>=0 finite
}
__device__ __forceinline__ float bf2f(unsigned short b) {
    return __uint_as_float(((unsigned)b) << 16);
}

// ---------------- kernel 1: per-row softmax -> bf16 probs + partials --------
// 512 threads = 8 waves = 8 rows/block. Block 0 zeroes the slot region
// (stream-ordered before pair_kernel; re-done every call -> replay safe).
__global__ __launch_bounds__(512) void row_kernel(
    const float* __restrict__ pred, const int* __restrict__ targets,
    const int* __restrict__ pred_choice, unsigned short* __restrict__ p16,
    float* __restrict__ sqn, float2* __restrict__ part_row,
    int* __restrict__ part_match, float* __restrict__ slotf,
    unsigned* __restrict__ subcnt, unsigned* __restrict__ master)
{
    __shared__ float2 lds_cf[8];
    __shared__ int lds_mt[8];

    if (blockIdx.x == 0) {
        for (int i = threadIdx.x; i < NSLOT * SLOTSTR; i += 512) {
            slotf[i] = 0.0f;
            subcnt[i] = 0u;
        }
        if (threadIdx.x == 0) *master = 0u;
    }

    int lane = threadIdx.x & 63;
    int wave = threadIdx.x >> 6;
    int row = blockIdx.x * 8 + wave;

    float v = (lane < CC) ? pred[(size_t)row * CC + lane] : -INFINITY;

    float m = v;
    #pragma unroll
    for (int off = 32; off; off >>= 1) m = fmaxf(m, __shfl_xor(m, off));

    float e = (lane < CC) ? __expf(v - m) : 0.0f;
    float s = e;
    #pragma unroll
    for (int off = 32; off; off >>= 1) s += __shfl_xor(s, off);

    float pv = e / s;                        // 0 for lanes >= 33

    unsigned short pb = f2bf(pv);            // bf16-rounded prob (0 stays 0)
    if (lane < RP) p16[(size_t)row * RP + lane] = pb;

    float pf = bf2f(pb);                     // sqn in ROUNDED space (matches MFMA dots)
    float sq = pf * pf;
    #pragma unroll
    for (int off = 32; off; off >>= 1) sq += __shfl_xor(sq, off);

    int t = targets[row];
    float vt = __shfl(v, t);
    float pt = __shfl(pv, t);
    float logpt = (vt - m) - __logf(s);

    if (lane == 0) {
        sqn[row] = sq;
        float om = 1.0f - pt;
        lds_cf[wave] = make_float2(-logpt, om * om);
        lds_mt[wave] = (t == pred_choice[row]) ? 1 : 0;
    }
    __syncthreads();
    if (threadIdx.x == 0) {
        float ce = 0.0f, fo = 0.0f;
        int mt = 0;
        #pragma unroll
        for (int i = 0; i < 8; i++) {
            ce += lds_cf[i].x; fo += lds_cf[i].y; mt += lds_mt[i];
        }
        part_row[blockIdx.x] = make_float2(ce, fo);
        part_match[blockIdx.x] = mt;
    }
}

// ---------------- kernel 2: 64x128 Gram tiles via bf16 MFMA + fence-free
// fused finalize. Each block: one i-tile x two j-tiles (A-frag + i-metadata
// reused). LDS linear 80B pitch -> conflict-free b128 reads. Partial sums
// through agent-scope atomics (L2-bypass, no __threadfence). 2-level
// completion counting: 33 blocks/slot -> slot winner bumps master -> 64th
// master = finalizer block.
__global__ __launch_bounds__(256) void pair_kernel(
    const unsigned short* __restrict__ p16, const float* __restrict__ sqn,
    const float2* __restrict__ part_row, const int* __restrict__ part_match,
    float* __restrict__ slotf, unsigned* __restrict__ subcnt,
    unsigned* __restrict__ master, float* __restrict__ out)
{
    __shared__ __align__(16) unsigned short spi[TILE * RP];
    __shared__ __align__(16) unsigned short spj[2][TILE * RP];
    __shared__ float ssqi[TILE], ssqj[2][TILE];
    __shared__ float red[4];
    __shared__ int lastFlag;
    __shared__ double lds_ce[4], lds_fo[4], lds_pr[4];
    __shared__ int lds_mt[4];

    int bid = blockIdx.x;
    int b = bid / NPB;
    int t = bid % NPB;

    // decode (ti, u): c(ti) = 32 - (ti>>1) j-pair blocks in row ti
    int ti = 0, rem = t;
    while (rem >= 32 - (ti >> 1)) { rem -= 32 - (ti >> 1); ++ti; }
    int tjA = ti + 2 * rem;
    bool hasB = (tjA + 1 < NTILES);
    bool diagA = (tjA == ti);

    int i0 = ti * TILE;
    int j0A = tjA * TILE;

    // linear staging: each tile is a contiguous 5120B block of p16
    const float4* srci  = (const float4*)(p16 + ((size_t)b * NN + i0) * RP);
    const float4* srcjA = (const float4*)(p16 + ((size_t)b * NN + j0A) * RP);
    float4* di  = (float4*)spi;
    float4* djA = (float4*)spj[0];
    for (int k = threadIdx.x; k < TILE * (RP / 8); k += 256) {  // 320 float4 each
        di[k]  = srci[k];
        djA[k] = srcjA[k];
    }
    if (hasB) {
        const float4* srcjB = srcjA + TILE * (RP / 8);          // next tile contiguous
        float4* djB = (float4*)spj[1];
        for (int k = threadIdx.x; k < TILE * (RP / 8); k += 256)
            djB[k] = srcjB[k];
    }
    if (threadIdx.x < TILE)
        ssqi[threadIdx.x] = sqn[b * NN + i0 + threadIdx.x];
    else if (threadIdx.x < 2 * TILE)
        ssqj[0][threadIdx.x - TILE] = sqn[b * NN + j0A + (threadIdx.x - TILE)];
    else if (hasB && threadIdx.x < 3 * TILE)
        ssqj[1][threadIdx.x - 2 * TILE] = sqn[b * NN + j0A + TILE + (threadIdx.x - 2 * TILE)];
    __syncthreads();

    int l = threadIdx.x & 63;
    int w = threadIdx.x >> 6;          // wave = 16-row strip of the i-tile
    int col = l & 15;
    int kc = l >> 4;                   // k-chunk 0..3 (8 bf16 each)

    // A fragment: rows 16w..16w+15 of i-tile, k = kc*8..kc*8+7 (reused x8 MFMAs)
    frag_ab afr = *(const frag_ab*)&spi[(16 * w + col) * RP + kc * 8];

    // per-lane row metadata (C layout: col=lane&15, row=(lane>>4)*4+r)
    float qi[4], c32a[4];
    #pragma unroll
    for (int r = 0; r < 4; r++) {
        int ir = 16 * w + kc * 4 + r;
        qi[r]   = ssqi[ir];
        c32a[r] = bf2f(spi[ir * RP + 32]);
    }
    int gi0 = i0 + 16 * w + kc * 4;    // gi = gi0 + r

    float ssum = 0.0f;

    #pragma unroll
    for (int jt = 0; jt < 2; jt++) {
        if (jt == 1 && !hasB) break;                 // block-uniform
        const unsigned short* spjx = spj[jt];
        const float* ssqx = ssqj[jt];
        int j0 = j0A + jt * TILE;
        bool dg = (jt == 0) && diagA;

        #pragma unroll
        for (int n = 0; n < 4; n++) {  // 16-col subtiles of this j-tile
            frag_ab bfr = *(const frag_ab*)&spjx[(16 * n + col) * RP + kc * 8];
            f32x4 acc = {0.0f, 0.0f, 0.0f, 0.0f};
            acc = __builtin_amdgcn_mfma_f32_16x16x32_bf16(afr, bfr, acc, 0, 0, 0);

            float c32b = bf2f(spjx[(16 * n + col) * RP + 32]);
            float qj   = ssqx[16 * n + col];
            int   gj   = j0 + 16 * n + col;

            #pragma unroll
            for (int r = 0; r < 4; r++) {
                float g  = fmaf(c32a[r], c32b, acc[r]);      // + class-32 term
                float d2 = fmaf(-2.0f, g, qi[r] + qj);
                float d  = fast_sqrt(fmaxf(d2, 0.0f));
                ssum += (!dg || gj > gi0 + r) ? d : 0.0f;    // strict upper on diag
            }
        }
    }

    #pragma unroll
    for (int off = 32; off; off >>= 1) ssum += __shfl_xor(ssum, off);
    if (l == 0) red[w] = ssum;
    __syncthreads();

    if (threadIdx.x == 0) {
        float blockSum = red[0] + red[1] + red[2] + red[3];
        int slot = (bid & (NSLOT - 1)) * SLOTSTR;
        __hip_atomic_fetch_add(&slotf[slot], blockSum,
                               __ATOMIC_RELAXED, __HIP_MEMORY_SCOPE_AGENT);
        asm volatile("s_waitcnt vmcnt(0)" ::: "memory");   // order fadd before count
        unsigned o = __hip_atomic_fetch_add(&subcnt[slot], 1u,
                                            __ATOMIC_RELAXED, __HIP_MEMORY_SCOPE_AGENT);
        int last = 0;
        if (o == (PAIRBLK / NSLOT) - 1) {                  // 33rd block of this slot
            unsigned o2 = __hip_atomic_fetch_add(master, 1u,
                                                 __ATOMIC_RELAXED, __HIP_MEMORY_SCOPE_AGENT);
            last = (o2 == NSLOT - 1);
        }
        lastFlag = last;
    }
    __syncthreads();
    if (!lastFlag) return;

    // ---- fused finalize (winner block only; slots coherent via agent atomics,
    //      part_* via kernel-boundary) ----
    double ce = 0.0, fo = 0.0, pr = 0.0;
    int mt = 0;
    for (int i = threadIdx.x; i < ROWBLK; i += 256) {
        float2 v = part_row[i];
        ce += (double)v.x;
        fo += (double)v.y;
        mt += part_match[i];
    }
    for (int i = threadIdx.x; i < NSLOT; i += 256)
        pr += (double)__hip_atomic_load(&slotf[i * SLOTSTR],
                                        __ATOMIC_RELAXED, __HIP_MEMORY_SCOPE_AGENT);

    #pragma unroll
    for (int off = 32; off; off >>= 1) {
        ce += __shfl_xor(ce, off);
        fo += __shfl_xor(fo, off);
        pr += __shfl_xor(pr, off);
        mt += __shfl_xor(mt, off);
    }
    if (l == 0) { lds_ce[w] = ce; lds_fo[w] = fo; lds_pr[w] = pr; lds_mt[w] = mt; }
    __syncthreads();
    if (threadIdx.x == 0) {
        double tce = lds_ce[0] + lds_ce[1] + lds_ce[2] + lds_ce[3];
        double tfo = lds_fo[0] + lds_fo[1] + lds_fo[2] + lds_fo[3];
        double tpr = lds_pr[0] + lds_pr[1] + lds_pr[2] + lds_pr[3];
        int    tmt = lds_mt[0] + lds_mt[1] + lds_mt[2] + lds_mt[3];

        double BN = (double)(BB * NN);
        double loss = (tce / BN) * (tfo / BN);
        double dice = 1.0 - 2.0 * ((double)tmt + 1.0) / (2.0 * BN + 1.0);
        double S = 2.0 * tpr;                    // full matrix sum (diag = 0)
        double mean_pred = S / (BN * (double)NN);
        double dml = 0.05 * log(0.05) - 0.05 * mean_pred;
        out[0] = (float)(loss + dice + dml);
    }
}

extern "C" void kernel_launch(void* const* d_in, const int* in_sizes, int n_in,
                              void* d_out, int out_size, void* d_ws, size_t ws_size,
                              hipStream_t stream)
{
    const float* pred        = (const float*)d_in[0];
    // d_in[1] = y_ohe: unused — the double-where provably collapses dis_map to 0.05
    const int*   targets     = (const int*)d_in[2];
    const int*   pred_choice = (const int*)d_in[3];

    char* ws = (char*)d_ws;
    size_t off = 0;
    unsigned short* p16 = (unsigned short*)ws;               // BB*NN*RP ushorts
    off += (size_t)BB * NN * RP * sizeof(unsigned short);
    float* sqn = (float*)(ws + off);
    off += (size_t)BB * NN * sizeof(float);
    off = (off + 127) & ~(size_t)127;
    float2* part_row = (float2*)(ws + off);                  // ROWBLK float2
    off += (size_t)ROWBLK * sizeof(float2);
    int* part_match = (int*)(ws + off);                      // ROWBLK int
    off += (size_t)ROWBLK * sizeof(int);
    off = (off + 127) & ~(size_t)127;
    float* slotf = (float*)(ws + off);                       // 64 slots x 128 B
    off += (size_t)NSLOT * SLOTSTR * sizeof(float);
    unsigned* subcnt = (unsigned*)(ws + off);                // 64 counters x 128 B
    off += (size_t)NSLOT * SLOTSTR * sizeof(unsigned);
    unsigned* master = (unsigned*)(ws + off);
    off += sizeof(unsigned);

    row_kernel<<<ROWBLK, 512, 0, stream>>>(pred, targets, pred_choice,
                                           p16, sqn, part_row, part_match,
                                           slotf, subcnt, master);
    pair_kernel<<<PAIRBLK, 256, 0, stream>>>(p16, sqn, part_row, part_match,
                                             slotf, subcnt, master, (float*)d_out);
}